// Round 10
// baseline (298.990 us; speedup 1.0000x reference)
//
#include <hip/hip_runtime.h>

// B=8, L=2048, C=256, D=32. Four attentions (ecg/pcg intra/inter),
// out = concat(inter + scalar*intra) -> (8,2048,512) f32.
//
// Pipeline:
//   1) hipMemsetAsync(d_out, 0); all four attentions atomically accumulate.
//   2) prep_kernel : fused deint (x -> xe/xp bf16) + wcat (weights -> WT[1280][256])
//   3) proj_kernel : xe/xp @ WT -> Q[4],K[4], V in VF layout VF[b][k8][vcol][8keys]
//   4) flash_kernel: 1024 blocks x 256 thr, vcols split 2-way across blocks (vh):
//      acc[4] (64 regs) + scalar densum -> fits __launch_bounds__(256,4) =
//      16 waves/CU (r9 was register-capped at ~2 waves/SIMD: acc[8]+den = 144
//      unified-file regs). V tile 16KB dbuf via global_load_lds; S^T+shfl P
//      transform; fixed-max exp2 softmax; den per query via lane-column sums +
//      shfl_xor(32); atomic f32 epilogue. QK/K-load redundancy x2 (small).

typedef __bf16 v8bf __attribute__((ext_vector_type(8)));
typedef float  v16f __attribute__((ext_vector_type(16)));
typedef unsigned int u32;

typedef __attribute__((address_space(1))) const void gvoid;
typedef __attribute__((address_space(3))) void svoid;

#define QSCALE 0.25500526817276613f  // log2(e)/sqrt(32)

union frag_u { u32 d[4]; v8bf v; };
union pk_u { unsigned short s[2]; u32 d; };

static __device__ inline u32 pack_bf16(float x, float y) {
  pk_u u;
  __bf16 a = (__bf16)x, b = (__bf16)y;
  u.s[0] = *(unsigned short*)&a;
  u.s[1] = *(unsigned short*)&b;
  return u.d;
}

// ---------------------------------------------------------------- prep (deint + wcat)
struct WcatArgs {
  const float* src[40];
  int c0[40];
  int dout[40];
  float scale[40];
  __bf16* wt;             // [1280][256]
};

__global__ __launch_bounds__(256) void prep_kernel(const float* __restrict__ x,
                                                   __bf16* __restrict__ xe,
                                                   __bf16* __restrict__ xp,
                                                   WcatArgs wa) {
  const int bid = blockIdx.x;
  if (bid < 2048) {
    // deinterleave: x f32 [16384][256][2] -> xe, xp bf16 [16384][256]
    const size_t i = (size_t)bid * 256 + threadIdx.x;
    const float4* xin = (const float4*)(x + i * 16);
    float4 a = xin[0], b = xin[1], c = xin[2], d = xin[3];
    v8bf ev, pv;
    ev[0]=(__bf16)a.x; ev[1]=(__bf16)a.z; ev[2]=(__bf16)b.x; ev[3]=(__bf16)b.z;
    ev[4]=(__bf16)c.x; ev[5]=(__bf16)c.z; ev[6]=(__bf16)d.x; ev[7]=(__bf16)d.z;
    pv[0]=(__bf16)a.y; pv[1]=(__bf16)a.w; pv[2]=(__bf16)b.y; pv[3]=(__bf16)b.w;
    pv[4]=(__bf16)c.y; pv[5]=(__bf16)c.w; pv[6]=(__bf16)d.y; pv[7]=(__bf16)d.w;
    *(v8bf*)(xe + i * 8) = ev;
    *(v8bf*)(xp + i * 8) = pv;
  } else {
    // weight pack: WT[r][k] = src[k][c0 + r%32] * scale
    const int r = bid - 2048, e = r >> 5, k = threadIdx.x;
    const float v = wa.src[e][(size_t)k * wa.dout[e] + wa.c0[e] + (r & 31)] * wa.scale[e];
    wa.wt[(size_t)r * 256 + k] = (__bf16)v;
  }
}

// ---------------------------------------------------------------- projections
struct ProjArgs {
  const __bf16* xe;
  const __bf16* xp;
  const __bf16* wt;
  __bf16* q[4];
  __bf16* k[4];
  __bf16* vt[4];   // VF layout: [b][k8][vcol][8 keys]
};

// grid (20 jobs, 128 row-tiles of 128), block 256 (4 waves x 32 rows, 64 cols).
__global__ __launch_bounds__(256) void proj_kernel(ProjArgs pa) {
  const int job = blockIdx.x;
  const int rb  = blockIdx.y * 128;
  const int tid = threadIdx.x;
  const int lane = tid & 63, w = tid >> 6;
  const int l31 = lane & 31, lh = lane >> 5;

  __shared__ __bf16 lds_B[64 * 264];     // rows 528B
  __shared__ __bf16 lds_A[2][128 * 72];  // dbuf BK=64, rows 144B

  int src, vcol0 = 0, vmode = 0;
  __bf16* dqk[2] = {nullptr, nullptr};
  __bf16* vdst = nullptr;
  if (job < 4) {
    switch (job) {
      case 0: src=0; dqk[0]=pa.q[0]; dqk[1]=pa.q[1]; break;
      case 1: src=0; dqk[0]=pa.k[0]; dqk[1]=pa.k[3]; break;
      case 2: src=1; dqk[0]=pa.q[2]; dqk[1]=pa.q[3]; break;
      default:src=1; dqk[0]=pa.k[1]; dqk[1]=pa.k[2]; break;
    }
  } else {
    const int vi = (job - 4) >> 2, t = (job - 4) & 3;
    const int vbuf = (vi==0) ? 0 : (vi==1) ? 3 : (vi==2) ? 1 : 2;
    vmode = 1; src = vi >> 1;
    vcol0 = t*64; vdst = pa.vt[vbuf];
  }

  const __bf16* X = src ? pa.xp : pa.xe;

  // B loads (once): WT rows job*64..+63
  int4 breg[8];
  int brow[8], bch[8];
#pragma unroll
  for (int i = 0; i < 8; ++i) {
    const int idx = tid + i*256;
    brow[i] = idx >> 5; bch[i] = idx & 31;
    breg[i] = *(const int4*)(pa.wt + ((size_t)(job*64 + brow[i])*256 + bch[i]*8));
  }
  int arow[4], ach[4];
#pragma unroll
  for (int i = 0; i < 4; ++i) {
    const int idx = tid + i*256;
    arow[i] = idx >> 3; ach[i] = idx & 7;
  }
  int4 areg[4];
#define LOAD_A(kb)                                                              \
  _Pragma("unroll")                                                             \
  for (int i = 0; i < 4; ++i)                                                   \
    areg[i] = *(const int4*)(X + ((size_t)(rb + arow[i])*256 + (kb)*64 + ach[i]*8));

#define WRITE_A(buf)                                                            \
  _Pragma("unroll")                                                             \
  for (int i = 0; i < 4; ++i)                                                   \
    *(int4*)&lds_A[buf][arow[i]*72 + ach[i]*8] = areg[i];

  LOAD_A(0)
#pragma unroll
  for (int i = 0; i < 8; ++i)
    *(int4*)&lds_B[brow[i]*264 + bch[i]*8] = breg[i];
  WRITE_A(0)
  LOAD_A(1)
  __syncthreads();

  v16f acc[2];
#pragma unroll
  for (int n = 0; n < 2; ++n)
#pragma unroll
    for (int i = 0; i < 16; ++i) acc[n][i] = 0.f;

  for (int kb = 0; kb < 4; ++kb) {
    if (kb < 3) WRITE_A((kb + 1) & 1)
    if (kb < 2) LOAD_A(kb + 2)
    const __bf16* ab = &lds_A[kb & 1][0];
#pragma unroll
    for (int kk = 0; kk < 4; ++kk) {
      const v8bf af = *(const v8bf*)&ab[(w*32 + l31)*72 + (kk*2 + lh)*8];
#pragma unroll
      for (int nt = 0; nt < 2; ++nt) {
        const v8bf bf = *(const v8bf*)&lds_B[(nt*32 + l31)*264 + kb*64 + kk*16 + lh*8];
        acc[nt] = __builtin_amdgcn_mfma_f32_32x32x16_bf16(af, bf, acc[nt], 0, 0, 0);
      }
    }
    __syncthreads();
  }

  if (!vmode) {
    // Q/K row-major [16384][32] (scale pre-folded into WT)
#pragma unroll
    for (int nt = 0; nt < 2; ++nt) {
      __bf16* dst = dqk[nt];
#pragma unroll
      for (int r = 0; r < 16; ++r) {
        const int row = rb + w*32 + (r & 3) + 8*(r >> 2) + 4*lh;
        dst[(size_t)row*32 + l31] = (__bf16)acc[nt][r];
      }
    }
  } else {
    // V: transpose 128keys x 64vcols tile through LDS, then write VF[b][k8][vcol]
    __bf16 (*lds_t)[136] = (__bf16 (*)[136])&lds_A[0][0];  // 64 x 272B rows
#pragma unroll
    for (int nt = 0; nt < 2; ++nt) {
#pragma unroll
      for (int r = 0; r < 16; ++r) {
        const int row = w*32 + (r & 3) + 8*(r >> 2) + 4*lh;
        lds_t[nt*32 + l31][row] = (__bf16)acc[nt][r];
      }
    }
    __syncthreads();
    const int bb = rb >> 11, k8base = (rb & 2047) >> 3;
    for (int i = tid; i < 1024; i += 256) {
      const int seg = i >> 6, vrow = i & 63;
      *(int4*)&vdst[(((size_t)bb*256 + k8base + seg)*256 + vcol0 + vrow)*8] =
          *(const int4*)&lds_t[vrow][seg*8];
    }
  }
}

// ---------------------------------------------------------------- flash attention
struct FlashArgs {
  const __bf16* q[4];
  const __bf16* k[4];
  const __bf16* v[4];   // VF layout
  const float* alpha;
  const float* gamma;
  float* out;
};

// 1024 blocks x 256 thr = exactly 4 blocks/CU at launch_bounds(256,4).
// flat = pair + 32*(2*qt + vh): pair%8 pins (att,bb) to an XCD.
// Wave: 32 q x 128 vcols (vh half), 32 kt of 64 keys. One-iteration software
// pipeline; den via per-lane column sums (no ones-MFMA, no den accumulator).
__global__ __launch_bounds__(256, 4) void flash_kernel(FlashArgs fa) {
  const int flat = blockIdx.x;
  const int pair = flat & 31, rest = flat >> 5;
  const int qt = rest >> 1, vh = rest & 1;
  const int att = pair & 3, bb = pair >> 2;
  const int tid = threadIdx.x;
  const int lane = tid & 63, w = tid >> 6;
  const int l31 = lane & 31, lh = lane >> 5;

  __shared__ __bf16 v_lds[2][8192];  // 2 x (8 k8 x 128 vcols x 8 keys) = 2 x 16KB

  const __bf16* Q  = fa.q[att] + (size_t)bb*2048*32;
  const __bf16* Kb = fa.k[att] + (size_t)bb*2048*32;
  const __bf16* VF = fa.v[att] + (size_t)bb*256*2048;  // VF[b][k8][vcol][8]
  float scv = 1.0f;
  if (att == 0) scv = fa.alpha[0];
  if (att == 2) scv = fa.gamma[0];
  const int zcol = (att >> 1) * 256 + vh * 128;

  // Q B-frags (resident): B[n=q=l31][k=d = c*16 + lh*8 + j]
  const int qrow = qt*128 + w*32 + l31;
  const v8bf qf0 = *(const v8bf*)&Q[(size_t)qrow*32 + lh*8];
  const v8bf qf1 = *(const v8bf*)&Q[(size_t)qrow*32 + 16 + lh*8];

  // staging: 16 chunks of 1KB; wave w takes chunks w*4..w*4+3.
  // chunk c: k8l = c>>1 (0..7), vquarter = c&1 (64-vcol groups within this half).
#define STAGE_V(buf, kt)                                                        \
  {                                                                             \
    const size_t kb8 = (size_t)(kt) * 8;                                        \
    _Pragma("unroll")                                                           \
    for (int i = 0; i < 4; ++i) {                                               \
      const int c = w*4 + i;                                                    \
      __builtin_amdgcn_global_load_lds(                                         \
          (gvoid*)&VF[((kb8 + (c>>1))*256 + vh*128 + (c&1)*64 + lane)*8],       \
          (svoid*)&v_lds[buf][((size_t)(c*64 + lane))*8], 16, 0, 0);            \
    }                                                                           \
  }

  // K A-frags: A[m=key = t*32+l31][k=d]
  v8bf kf[2][2];
#define LOAD_K(kb)                                                              \
  _Pragma("unroll")                                                             \
  for (int t = 0; t < 2; ++t)                                                   \
    _Pragma("unroll")                                                           \
    for (int c = 0; c < 2; ++c)                                                 \
      kf[t][c] = *(const v8bf*)&Kb[((size_t)((kb) + t*32 + l31))*32 + c*16 + lh*8];

  v16f acc[4];
#pragma unroll
  for (int n = 0; n < 4; ++n)
#pragma unroll
    for (int i = 0; i < 16; ++i) acc[n][i] = 0.f;
  float densum = 0.f;   // running sum of P for query l31 (this lane's S^T column)

  v8bf pf[4];  // P A-frags, always built one iteration ahead

  // S^T -> exp2 (+ den column-sum) -> lane-pair shfl -> pf
  auto compute_pf = [&]() {
    v16f st0, st1;
#pragma unroll
    for (int i = 0; i < 16; ++i) { st0[i] = 0.f; st1[i] = 0.f; }
    st0 = __builtin_amdgcn_mfma_f32_32x32x16_bf16(kf[0][0], qf0, st0, 0, 0, 0);
    st0 = __builtin_amdgcn_mfma_f32_32x32x16_bf16(kf[0][1], qf1, st0, 0, 0, 0);
    st1 = __builtin_amdgcn_mfma_f32_32x32x16_bf16(kf[1][0], qf0, st1, 0, 0, 0);
    st1 = __builtin_amdgcn_mfma_f32_32x32x16_bf16(kf[1][1], qf1, st1, 0, 0, 0);

    float lsum = 0.f;
    u32 pk0[8], pk1[8];
#pragma unroll
    for (int i = 0; i < 8; ++i) {
      const float e0 = __builtin_exp2f(st0[2*i]), e1 = __builtin_exp2f(st0[2*i + 1]);
      lsum += e0 + e1;
      pk0[i] = pack_bf16(e0, e1);
    }
#pragma unroll
    for (int i = 0; i < 8; ++i) {
      const float e0 = __builtin_exp2f(st1[2*i]), e1 = __builtin_exp2f(st1[2*i + 1]);
      lsum += e0 + e1;
      pk1[i] = pack_bf16(e0, e1);
    }
    // this lane holds 32 of the 64 key-values of its query; partner (lane^32) the rest
    densum += lsum + __shfl_xor(lsum, 32, 64);

#pragma unroll
    for (int half = 0; half < 2; ++half) {
      const u32* pk = half ? pk1 : pk0;
#pragma unroll
      for (int f2 = 0; f2 < 2; ++f2) {
        const u32 keep0 = lh ? pk[f2*4 + 2] : pk[f2*4 + 0];
        const u32 keep1 = lh ? pk[f2*4 + 3] : pk[f2*4 + 1];
        const u32 send0 = lh ? pk[f2*4 + 0] : pk[f2*4 + 2];
        const u32 send1 = lh ? pk[f2*4 + 1] : pk[f2*4 + 3];
        const u32 recv0 = (u32)__shfl_xor((int)send0, 32, 64);
        const u32 recv1 = (u32)__shfl_xor((int)send1, 32, 64);
        frag_u fu;
        fu.d[0] = lh ? recv0 : keep0;
        fu.d[1] = lh ? recv1 : keep1;
        fu.d[2] = lh ? keep0 : recv0;
        fu.d[3] = lh ? keep1 : recv1;
        pf[half*2 + f2] = fu.v;
      }
    }
  };

  // prologue
  STAGE_V(0, 0)
  LOAD_K(0)
  compute_pf();
  __syncthreads();

  for (int kt = 0; kt < 32; ++kt) {
    const int cur = kt & 1;
    if (kt < 31) {
      STAGE_V(cur ^ 1, kt + 1)
      LOAD_K((kt + 1) * 64)
    }

    // PV burst with pf from the previous iteration (deps: LDS cur buffer only)
    const __bf16* vb = &v_lds[cur][0];
#pragma unroll
    for (int kc = 0; kc < 4; ++kc) {
      const __bf16* vrow = &vb[(size_t)((kc*2 + lh)*128)*8];
#pragma unroll
      for (int nt = 0; nt < 4; ++nt) {
        const v8bf vf = *(const v8bf*)&vrow[(size_t)(nt*32 + l31)*8];
        acc[nt] = __builtin_amdgcn_mfma_f32_32x32x16_bf16(pf[kc], vf, acc[nt], 0, 0, 0);
      }
    }

    if (kt < 31) compute_pf();
    __syncthreads();  // drains staging vmcnt + all waves done with cur buffer
  }

  // epilogue: atomic accumulate scv * acc / den; den for query q lives in lane q
  float* outp = fa.out + (size_t)(bb*2048 + qt*128 + w*32) * 512 + zcol;
#pragma unroll
  for (int r = 0; r < 16; ++r) {
    const int row = (r & 3) + 8*(r >> 2) + 4*lh;
    const float qd = __shfl(densum, row, 64);
    const float f = scv / qd;
#pragma unroll
    for (int nt = 0; nt < 4; ++nt)
      unsafeAtomicAdd(&outp[(size_t)row*512 + nt*32 + l31], acc[nt][r] * f);
  }
}

// ---------------------------------------------------------------- launch
extern "C" void kernel_launch(void* const* d_in, const int* in_sizes, int n_in,
                              void* d_out, int out_size, void* d_ws, size_t ws_size,
                              hipStream_t stream) {
  (void)in_sizes; (void)n_in; (void)out_size; (void)ws_size;

  __bf16* wsp = (__bf16*)d_ws;
  const size_t XE = (size_t)16384 * 256;
  const size_t QK = (size_t)16384 * 32;
  const size_t VT = (size_t)8 * 256 * 2048;

  __bf16* xe = wsp;
  __bf16* xp = wsp + XE;
  __bf16* base = wsp + 2*XE;

  ProjArgs pa;
  pa.xe = xe; pa.xp = xp;
  const float* x = (const float*)d_in[0];
  const float* wsrc[12];
  for (int i = 0; i < 12; ++i) wsrc[i] = (const float*)d_in[1 + i];
  for (int i = 0; i < 4; ++i) pa.q[i]  = base + (size_t)i * QK;
  for (int i = 0; i < 4; ++i) pa.k[i]  = base + (size_t)(4 + i) * QK;
  for (int i = 0; i < 4; ++i) pa.vt[i] = base + 8*QK + (size_t)i * VT;
  __bf16* wt = base + 8*QK + 4*VT;
  pa.wt = wt;

  WcatArgs wa;
  wa.wt = wt;
  const int qk_w[4][2] = {{0, 3}, {1, 10}, {6, 9}, {4, 7}};
  const float qk_s[4] = {QSCALE, 1.0f, QSCALE, 1.0f};
  for (int g = 0; g < 4; ++g)
    for (int h = 0; h < 2; ++h) {
      const int e = g*2 + h;
      wa.src[e] = wsrc[qk_w[g][h]];
      wa.c0[e] = 0; wa.dout[e] = 32; wa.scale[e] = qk_s[g];
    }
  const int v_w[4] = {2, 11, 5, 8};
  for (int vi = 0; vi < 4; ++vi)
    for (int t = 0; t < 4; ++t)
      for (int h = 0; h < 2; ++h) {
        const int e = (4 + vi*4 + t)*2 + h;
        wa.src[e] = wsrc[v_w[vi]];
        wa.c0[e] = t*64 + h*32; wa.dout[e] = 256; wa.scale[e] = 1.0f;
      }

  hipMemsetAsync(d_out, 0, (size_t)8*2048*512*4, stream);
  hipLaunchKernelGGL(prep_kernel, dim3(2048 + 1280), dim3(256), 0, stream, x, xe, xp, wa);
  hipLaunchKernelGGL(proj_kernel, dim3(20, 128), dim3(256), 0, stream, pa);

  FlashArgs fl;
  for (int i = 0; i < 4; ++i) { fl.q[i] = pa.q[i]; fl.k[i] = pa.k[i]; fl.v[i] = pa.vt[i]; }
  fl.alpha = (const float*)d_in[13];
  fl.gamma = (const float*)d_in[14];
  fl.out = (float*)d_out;
  hipLaunchKernelGGL(flash_kernel, dim3(1024), dim3(256), 0, stream, fl);
}